// Round 1
// baseline (168.349 us; speedup 1.0000x reference)
//
#include <hip/hip_runtime.h>

#define BATCH 512
#define ZDIM 256

// ---------------------------------------------------------------- helpers

__device__ __forceinline__ float fast_exp2(float x) {
#if __has_builtin(__builtin_amdgcn_exp2f)
    return __builtin_amdgcn_exp2f(x);   // v_exp_f32 (2^x)
#else
    return exp2f(x);
#endif
}

__device__ __forceinline__ float wave_reduce_sum(float v) {
#pragma unroll
    for (int off = 32; off > 0; off >>= 1)
        v += __shfl_down(v, off, 64);
    return v;
}

__device__ __forceinline__ float wave_reduce_max(float v) {
#pragma unroll
    for (int off = 32; off > 0; off >>= 1)
        v = fmaxf(v, __shfl_down(v, off, 64));
    return v;
}

// block of 256 threads = 4 waves; result broadcast to all threads
__device__ __forceinline__ float block_sum256(float v, float* red) {
    float w = wave_reduce_sum(v);
    if ((threadIdx.x & 63) == 0) red[threadIdx.x >> 6] = w;
    __syncthreads();
    float r = red[0] + red[1] + red[2] + red[3];
    __syncthreads();
    return r;
}

// ---------------------------------------------------------------- kernels

// BCE reconstruction sum over data/recon (HBM-bound, 50 MB)
__global__ __launch_bounds__(256) void k_rec(const float4* __restrict__ d,
                                             const float4* __restrict__ r,
                                             float* __restrict__ acc, int n4) {
    __shared__ float red[4];
    float s = 0.f;
    int stride = gridDim.x * blockDim.x;
    for (int idx = blockIdx.x * blockDim.x + threadIdx.x; idx < n4; idx += stride) {
        float4 dv = d[idx];
        float4 rv = r[idx];
        s += dv.x * __logf(rv.x) + (1.f - dv.x) * __logf(1.f - rv.x);
        s += dv.y * __logf(rv.y) + (1.f - dv.y) * __logf(1.f - rv.y);
        s += dv.z * __logf(rv.z) + (1.f - dv.z) * __logf(1.f - rv.z);
        s += dv.w * __logf(rv.w) + (1.f - dv.w) * __logf(1.f - rv.w);
    }
    float t = block_sum256(s, red);
    if (threadIdx.x == 0) atomicAdd(acc + 0, t);
}

// Precompute per-(j,k) tables + c_j + dw_kl. Block = j, thread = k.
// evl  [j][k] : float2{ -0.5*exp(lv)*log2e , -0.5*(lv+LOG2PI)*log2e }  (base-2)
// e2wT [k][j] : float2{ -0.5*exp(lv)       , mu*exp(lv) }              (natural)
// cj   [j]    : sum_k( mu^2*(-0.5*exp(lv)) - 0.5*(lv+LOG2PI) )
__global__ __launch_bounds__(256) void k_pre(const float* __restrict__ mu,
                                             const float* __restrict__ logvar,
                                             float2* __restrict__ evl,
                                             float2* __restrict__ e2wT,
                                             float* __restrict__ cj,
                                             float* __restrict__ acc) {
    __shared__ float red[4];
    int j = blockIdx.x, k = threadIdx.x;
    float m = mu[j * ZDIM + k];
    float lv = logvar[j * ZDIM + k];
    float ev = __expf(lv);
    float e2n = -0.5f * ev;
    float lcn = -0.5f * (lv + 1.8378770664093453f);   // -0.5*(lv + LOG2PI)
    const float L2E = 1.4426950408889634f;
    evl[j * ZDIM + k] = make_float2(e2n * L2E, lcn * L2E);
    e2wT[k * BATCH + j] = make_float2(e2n, m * ev);
    float cpart = m * m * e2n + lcn;
    float csum = block_sum256(cpart, red);
    if (k == 0) cj[j] = csum;
    float dw = -0.5f * lv + 0.5f * __expf(lv + m * m) - 0.5f;
    float dsum = block_sum256(dw, red);
    if (k == 0) atomicAdd(acc + 1, dsum);
}

// prodmarginals partials: for (i,k), sum_j exp(v[i,j,k]) over a j-chunk.
// Grid (B/8, 8); block thread = k. TI=8 i's per wg, 64 j's per chunk.
// No max-shift needed: v <= ~0.3 and >= ~-15 -> fp32 exp safe.
__global__ __launch_bounds__(256) void k_pm(const float* __restrict__ lat,
                                            const float2* __restrict__ evl,
                                            const float* __restrict__ mu,
                                            float* __restrict__ part) {
    int k = threadIdx.x;
    int i0 = blockIdx.x * 8;
    int j0 = blockIdx.y * 64;
    float s[8], a[8];
#pragma unroll
    for (int i = 0; i < 8; i++) {
        s[i] = lat[(i0 + i) * ZDIM + k];
        a[i] = 0.f;
    }
    for (int j = j0; j < j0 + 64; j++) {
        float2 el = evl[j * ZDIM + k];
        float m = mu[j * ZDIM + k];
#pragma unroll
        for (int i = 0; i < 8; i++) {
            float dd = s[i] - m;
            float v = fmaf(dd * dd, el.x, el.y);   // log2-domain density
            a[i] += fast_exp2(v);
        }
    }
#pragma unroll
    for (int i = 0; i < 8; i++)
        part[(blockIdx.y * BATCH + i0 + i) * ZDIM + k] = a[i];
}

// merge j-chunk partials -> prodmarg_raw[i] = sum_k ln(sum_j exp(v))
__global__ __launch_bounds__(256) void k_pmerge(const float* __restrict__ part,
                                                float* __restrict__ prod) {
    __shared__ float red[4];
    int i = blockIdx.x, k = threadIdx.x;
    float s = 0.f;
#pragma unroll
    for (int jc = 0; jc < 8; jc++)
        s += part[(jc * BATCH + i) * ZDIM + k];
    float lg = __logf(s);
    float tot = block_sum256(lg, red);
    if (k == 0) prod[i] = tot;
}

// S[i,j] = sum_k s*(s*e2 + w) + c_j  (dual-FMA "GEMM", natural log scale)
// Grid (B/4, 2); thread = j within 256-chunk; 4 i's per wg staged in LDS.
__global__ __launch_bounds__(256) void k_smat(const float* __restrict__ lat,
                                              const float2* __restrict__ e2wT,
                                              const float* __restrict__ cj,
                                              float* __restrict__ smat) {
    __shared__ float ss[4 * ZDIM];
    int t = threadIdx.x;
    int i0 = blockIdx.x * 4;
    int j = blockIdx.y * 256 + t;
    for (int idx = t; idx < 4 * ZDIM; idx += 256)
        ss[idx] = lat[i0 * ZDIM + idx];
    __syncthreads();
    float a0 = 0.f, a1 = 0.f, a2 = 0.f, a3 = 0.f;
#pragma unroll 4
    for (int k = 0; k < ZDIM; k++) {
        float2 ew = e2wT[k * BATCH + j];
        float s0 = ss[0 * ZDIM + k];
        float s1 = ss[1 * ZDIM + k];
        float s2 = ss[2 * ZDIM + k];
        float s3 = ss[3 * ZDIM + k];
        a0 = fmaf(s0, fmaf(s0, ew.x, ew.y), a0);
        a1 = fmaf(s1, fmaf(s1, ew.x, ew.y), a1);
        a2 = fmaf(s2, fmaf(s2, ew.x, ew.y), a2);
        a3 = fmaf(s3, fmaf(s3, ew.x, ew.y), a3);
    }
    float c = cj[j];
    smat[(i0 + 0) * BATCH + j] = a0 + c;
    smat[(i0 + 1) * BATCH + j] = a1 + c;
    smat[(i0 + 2) * BATCH + j] = a2 + c;
    smat[(i0 + 3) * BATCH + j] = a3 + c;
}

// per-i: logqz = lse_j(S[i,j]) (max-shifted; S ~ -360), combine with prod
__global__ __launch_bounds__(256) void k_tc(const float* __restrict__ smat,
                                            const float* __restrict__ prod,
                                            const int* __restrict__ dsz,
                                            float* __restrict__ acc) {
    __shared__ float red[4];
    int i = blockIdx.x, t = threadIdx.x;
    float v1 = smat[i * BATCH + t];
    float v2 = smat[i * BATCH + 256 + t];
    float m = wave_reduce_max(fmaxf(v1, v2));
    if ((t & 63) == 0) red[t >> 6] = m;
    __syncthreads();
    m = fmaxf(fmaxf(red[0], red[1]), fmaxf(red[2], red[3]));
    __syncthreads();
    float e = __expf(v1 - m) + __expf(v2 - m);
    float sum = block_sum256(e, red);
    if (t == 0) {
        float log_norm = __logf(512.f) + __logf((float)dsz[0]);
        float logqz = m + __logf(sum) - log_norm;
        float pm = prod[i] - 256.f * log_norm;   // Z * log_norm
        atomicAdd(acc + 2, logqz - pm);
    }
}

__global__ void k_final(const float* __restrict__ acc, float* __restrict__ out) {
    if (threadIdx.x == 0)
        out[0] = (acc[1] + acc[2] - acc[0]) * (1.f / 512.f);
}

// ---------------------------------------------------------------- launch

extern "C" void kernel_launch(void* const* d_in, const int* in_sizes, int n_in,
                              void* d_out, int out_size, void* d_ws, size_t ws_size,
                              hipStream_t stream) {
    const float* data   = (const float*)d_in[0];
    const float* recon  = (const float*)d_in[1];
    const float* lat    = (const float*)d_in[2];
    const float* mu     = (const float*)d_in[3];
    const float* logvar = (const float*)d_in[4];
    const int*   dsz    = (const int*)d_in[5];
    float* out = (float*)d_out;

    // workspace layout (float offsets)
    float*  ws   = (float*)d_ws;
    float*  acc  = ws;                              // [0]=rec_sum [1]=dwkl [2]=tc
    float2* evl  = (float2*)(ws + 64);              // 131072 float2
    float2* e2wT = (float2*)(ws + 64 + 262144);     // 131072 float2
    float*  cj   = ws + 64 + 524288;                // 512
    float*  prod = cj + 512;                        // 512
    float*  part = prod + 512;                      // 8*131072 = 1048576
    float*  smat = part + 1048576;                  // 262144

    hipMemsetAsync(d_ws, 0, 256, stream);           // zero accumulators

    int n4 = in_sizes[0] / 4;
    k_rec<<<1024, 256, 0, stream>>>((const float4*)data, (const float4*)recon, acc, n4);
    k_pre<<<512, 256, 0, stream>>>(mu, logvar, evl, e2wT, cj, acc);
    k_pm<<<dim3(64, 8), 256, 0, stream>>>(lat, evl, mu, part);
    k_pmerge<<<512, 256, 0, stream>>>(part, prod);
    k_smat<<<dim3(128, 2), 256, 0, stream>>>(lat, e2wT, cj, smat);
    k_tc<<<512, 256, 0, stream>>>(smat, prod, dsz, acc);
    k_final<<<1, 64, 0, stream>>>(acc, out);
}

// Round 2
// 154.208 us; speedup vs baseline: 1.0917x; 1.0917x over previous
//
#include <hip/hip_runtime.h>

#define BATCH 512
#define ZDIM 256

// ---------------------------------------------------------------- helpers

__device__ __forceinline__ float fast_exp2(float x) {
#if __has_builtin(__builtin_amdgcn_exp2f)
    return __builtin_amdgcn_exp2f(x);   // v_exp_f32 (2^x)
#else
    return exp2f(x);
#endif
}

__device__ __forceinline__ float wave_reduce_sum(float v) {
#pragma unroll
    for (int off = 32; off > 0; off >>= 1)
        v += __shfl_down(v, off, 64);
    return v;
}

__device__ __forceinline__ float wave_reduce_max(float v) {
#pragma unroll
    for (int off = 32; off > 0; off >>= 1)
        v = fmaxf(v, __shfl_down(v, off, 64));
    return v;
}

// block of 256 threads = 4 waves; result broadcast to all threads
__device__ __forceinline__ float block_sum256(float v, float* red) {
    float w = wave_reduce_sum(v);
    if ((threadIdx.x & 63) == 0) red[threadIdx.x >> 6] = w;
    __syncthreads();
    float r = red[0] + red[1] + red[2] + red[3];
    __syncthreads();
    return r;
}

// ---------------------------------------------------------------- kernels

// D1: blocks [0,1024) = BCE reconstruction sum; blocks [1024,1536) = tables+dwkl
__global__ __launch_bounds__(256) void k_phase1(
    const float4* __restrict__ d, const float4* __restrict__ r, int n4,
    const float* __restrict__ mu, const float* __restrict__ logvar,
    float2* __restrict__ evl, float2* __restrict__ e2wT,
    float* __restrict__ cj, float* __restrict__ acc) {
    __shared__ float red[4];
    int b = blockIdx.x;
    if (b < 1024) {
        float s = 0.f;
        int stride = 1024 * 256;
        for (int idx = b * 256 + threadIdx.x; idx < n4; idx += stride) {
            float4 dv = d[idx];
            float4 rv = r[idx];
            s += dv.x * __logf(rv.x) + (1.f - dv.x) * __logf(1.f - rv.x);
            s += dv.y * __logf(rv.y) + (1.f - dv.y) * __logf(1.f - rv.y);
            s += dv.z * __logf(rv.z) + (1.f - dv.z) * __logf(1.f - rv.z);
            s += dv.w * __logf(rv.w) + (1.f - dv.w) * __logf(1.f - rv.w);
        }
        float t = block_sum256(s, red);
        if (threadIdx.x == 0) atomicAdd(acc + 0, t);
    } else {
        int j = b - 1024, k = threadIdx.x;
        float m = mu[j * ZDIM + k];
        float lv = logvar[j * ZDIM + k];
        float ev = __expf(lv);
        float e2n = -0.5f * ev;
        float lcn = -0.5f * (lv + 1.8378770664093453f);   // -0.5*(lv + LOG2PI)
        const float L2E = 1.4426950408889634f;
        evl[j * ZDIM + k] = make_float2(e2n * L2E, lcn * L2E);
        e2wT[k * BATCH + j] = make_float2(e2n, m * ev);
        float cpart = m * m * e2n + lcn;
        float csum = block_sum256(cpart, red);
        if (k == 0) cj[j] = csum;
        float dw = -0.5f * lv + 0.5f * __expf(lv + m * m) - 0.5f;
        float dsum = block_sum256(dw, red);
        if (k == 0) atomicAdd(acc + 1, dsum);
    }
}

// D2: blocks [0,512) = pm partials (8 i's x 64 j's); [512,768) = S matrix
__global__ __launch_bounds__(256) void k_phase2(
    const float* __restrict__ lat, const float2* __restrict__ evl,
    const float* __restrict__ mu, float* __restrict__ part,
    const float2* __restrict__ e2wT, const float* __restrict__ cj,
    float* __restrict__ smat) {
    __shared__ float ss[4 * ZDIM];
    int b = blockIdx.x, t = threadIdx.x;
    if (b < 512) {
        int bx = b >> 3, by = b & 7;
        int i0 = bx * 8, j0 = by * 64;
        float s[8], a[8];
#pragma unroll
        for (int i = 0; i < 8; i++) {
            s[i] = lat[(i0 + i) * ZDIM + t];
            a[i] = 0.f;
        }
        for (int j = j0; j < j0 + 64; j++) {
            float2 el = evl[j * ZDIM + t];
            float m = mu[j * ZDIM + t];
#pragma unroll
            for (int i = 0; i < 8; i++) {
                float dd = s[i] - m;
                float v = fmaf(dd * dd, el.x, el.y);   // log2-domain density
                a[i] += fast_exp2(v);
            }
        }
#pragma unroll
        for (int i = 0; i < 8; i++)
            part[(by * BATCH + i0 + i) * ZDIM + t] = a[i];
    } else {
        int sb = b - 512;
        int i0 = (sb >> 1) * 4;
        int j = (sb & 1) * 256 + t;
        for (int idx = t; idx < 4 * ZDIM; idx += 256)
            ss[idx] = lat[i0 * ZDIM + idx];
        __syncthreads();
        float a0 = 0.f, a1 = 0.f, a2 = 0.f, a3 = 0.f;
#pragma unroll 4
        for (int k = 0; k < ZDIM; k++) {
            float2 ew = e2wT[k * BATCH + j];
            float s0 = ss[0 * ZDIM + k];
            float s1 = ss[1 * ZDIM + k];
            float s2 = ss[2 * ZDIM + k];
            float s3 = ss[3 * ZDIM + k];
            a0 = fmaf(s0, fmaf(s0, ew.x, ew.y), a0);
            a1 = fmaf(s1, fmaf(s1, ew.x, ew.y), a1);
            a2 = fmaf(s2, fmaf(s2, ew.x, ew.y), a2);
            a3 = fmaf(s3, fmaf(s3, ew.x, ew.y), a3);
        }
        float c = cj[j];
        smat[(i0 + 0) * BATCH + j] = a0 + c;
        smat[(i0 + 1) * BATCH + j] = a1 + c;
        smat[(i0 + 2) * BATCH + j] = a2 + c;
        smat[(i0 + 3) * BATCH + j] = a3 + c;
    }
}

// D3: block i = merge pm partials -> prod_i, lse over S row i, tc accumulate;
// last block to finish computes the final scalar.
__global__ __launch_bounds__(256) void k_phase3(
    const float* __restrict__ part, const float* __restrict__ smat,
    const int* __restrict__ dsz, float* __restrict__ acc,
    unsigned int* __restrict__ cnt, float* __restrict__ out) {
    __shared__ float red[4];
    int i = blockIdx.x, t = threadIdx.x;
    // merge j-chunk partials -> prod_i = sum_k ln(sum_j exp(v))
    float s = 0.f;
#pragma unroll
    for (int jc = 0; jc < 8; jc++)
        s += part[(jc * BATCH + i) * ZDIM + t];
    float prod_i = block_sum256(__logf(s), red);
    // lse over S row i (max-shifted; S ~ -360)
    float v1 = smat[i * BATCH + t];
    float v2 = smat[i * BATCH + 256 + t];
    float m = wave_reduce_max(fmaxf(v1, v2));
    if ((t & 63) == 0) red[t >> 6] = m;
    __syncthreads();
    m = fmaxf(fmaxf(red[0], red[1]), fmaxf(red[2], red[3]));
    __syncthreads();
    float e = __expf(v1 - m) + __expf(v2 - m);
    float sum = block_sum256(e, red);
    if (t == 0) {
        float log_norm = __logf(512.f) + __logf((float)dsz[0]);
        float logqz = m + __logf(sum) - log_norm;
        float pm = prod_i - 256.f * log_norm;   // Z * log_norm
        atomicAdd(acc + 2, logqz - pm);
        __threadfence();
        unsigned int old = atomicAdd(cnt, 1u);
        if (old == BATCH - 1) {
            // atomic reads for device-scope coherence of acc
            float a0 = atomicAdd(acc + 0, 0.f);
            float a1 = atomicAdd(acc + 1, 0.f);
            float a2 = atomicAdd(acc + 2, 0.f);
            out[0] = (a1 + a2 - a0) * (1.f / 512.f);
        }
    }
}

// ---------------------------------------------------------------- launch

extern "C" void kernel_launch(void* const* d_in, const int* in_sizes, int n_in,
                              void* d_out, int out_size, void* d_ws, size_t ws_size,
                              hipStream_t stream) {
    const float* data   = (const float*)d_in[0];
    const float* recon  = (const float*)d_in[1];
    const float* lat    = (const float*)d_in[2];
    const float* mu     = (const float*)d_in[3];
    const float* logvar = (const float*)d_in[4];
    const int*   dsz    = (const int*)d_in[5];
    float* out = (float*)d_out;

    // workspace layout (float offsets)
    float*  ws   = (float*)d_ws;
    float*  acc  = ws;                              // [0]=rec_sum [1]=dwkl [2]=tc
    unsigned int* cnt = (unsigned int*)(ws + 8);    // termination counter
    float2* evl  = (float2*)(ws + 64);              // 131072 float2
    float2* e2wT = (float2*)(ws + 64 + 262144);     // 131072 float2
    float*  cj   = ws + 64 + 524288;                // 512
    float*  part = cj + 512;                        // 8*131072 = 1048576
    float*  smat = part + 1048576;                  // 262144

    hipMemsetAsync(d_ws, 0, 256, stream);           // zero accumulators + counter

    int n4 = in_sizes[0] / 4;
    k_phase1<<<1536, 256, 0, stream>>>((const float4*)data, (const float4*)recon, n4,
                                       mu, logvar, evl, e2wT, cj, acc);
    k_phase2<<<768, 256, 0, stream>>>(lat, evl, mu, part, e2wT, cj, smat);
    k_phase3<<<512, 256, 0, stream>>>(part, smat, dsz, acc, cnt, out);
}

// Round 3
// 132.393 us; speedup vs baseline: 1.2716x; 1.1648x over previous
//
#include <hip/hip_runtime.h>

#define BATCH 512
#define ZDIM 256

// ---------------------------------------------------------------- helpers

__device__ __forceinline__ float fast_exp2(float x) {
#if __has_builtin(__builtin_amdgcn_exp2f)
    return __builtin_amdgcn_exp2f(x);   // v_exp_f32 (2^x)
#else
    return exp2f(x);
#endif
}

__device__ __forceinline__ float wave_reduce_sum(float v) {
#pragma unroll
    for (int off = 32; off > 0; off >>= 1)
        v += __shfl_down(v, off, 64);
    return v;
}

__device__ __forceinline__ float wave_reduce_max(float v) {
#pragma unroll
    for (int off = 32; off > 0; off >>= 1)
        v = fmaxf(v, __shfl_down(v, off, 64));
    return v;
}

// block of 256 threads = 4 waves; result broadcast to all threads
__device__ __forceinline__ float block_sum256(float v, float* red) {
    float w = wave_reduce_sum(v);
    if ((threadIdx.x & 63) == 0) red[threadIdx.x >> 6] = w;
    __syncthreads();
    float r = red[0] + red[1] + red[2] + red[3];
    __syncthreads();
    return r;
}

// ---------------------------------------------------------------- kernels

// K1 (512 blocks): per-(j,k) tables + cj + dwrow[j]; block 0 zeroes cnt.
// evl  [j][k] : float2{ -0.5*exp(lv)*log2e , -0.5*(lv+LOG2PI)*log2e }  (base-2)
// e2wT [k][j] : float2{ -0.5*exp(lv)       , mu*exp(lv) }              (natural)
// cj   [j]    : sum_k( mu^2*(-0.5*exp(lv)) - 0.5*(lv+LOG2PI) )
__global__ __launch_bounds__(256) void k_tables(
    const float* __restrict__ mu, const float* __restrict__ logvar,
    float2* __restrict__ evl, float2* __restrict__ e2wT,
    float* __restrict__ cj, float* __restrict__ dwrow,
    unsigned int* __restrict__ cnt) {
    __shared__ float red[4];
    int j = blockIdx.x, k = threadIdx.x;
    if (j == 0 && k == 0) cnt[0] = 0u;   // init last-block counter for K3
    float m = mu[j * ZDIM + k];
    float lv = logvar[j * ZDIM + k];
    float ev = __expf(lv);
    float e2n = -0.5f * ev;
    float lcn = -0.5f * (lv + 1.8378770664093453f);   // -0.5*(lv + LOG2PI)
    const float L2E = 1.4426950408889634f;
    evl[j * ZDIM + k] = make_float2(e2n * L2E, lcn * L2E);
    e2wT[k * BATCH + j] = make_float2(e2n, m * ev);
    float cpart = m * m * e2n + lcn;
    float csum = block_sum256(cpart, red);
    if (k == 0) cj[j] = csum;
    float dw = -0.5f * lv + 0.5f * __expf(lv + m * m) - 0.5f;
    float dsum = block_sum256(dw, red);
    if (k == 0) dwrow[j] = dsum;
}

// K2 (1280 blocks): [0,512) rec BCE; [512,1024) pm partials; [1024,1280) smat
__global__ __launch_bounds__(256) void k_bulk(
    const float4* __restrict__ d, const float4* __restrict__ r,
    const float* __restrict__ lat, const float2* __restrict__ evl,
    const float* __restrict__ mu, float* __restrict__ part,
    const float2* __restrict__ e2wT, const float* __restrict__ cj,
    float* __restrict__ smat, float* __restrict__ recpart) {
    __shared__ float ss[4 * ZDIM];
    int b = blockIdx.x, t = threadIdx.x;
    if (b < 512) {
        // BCE: n4 = 512*3*64*64/4 = 1572864 = 131072 threads * 12 iters
        __shared__ float red[4];
        float s = 0.f;
        int base = b * 256 + t;
#pragma unroll 4
        for (int it = 0; it < 12; ++it) {
            int idx = base + it * 131072;
            float4 dv = d[idx];
            float4 rv = r[idx];
            s += dv.x * __logf(rv.x) + (1.f - dv.x) * __logf(1.f - rv.x);
            s += dv.y * __logf(rv.y) + (1.f - dv.y) * __logf(1.f - rv.y);
            s += dv.z * __logf(rv.z) + (1.f - dv.z) * __logf(1.f - rv.z);
            s += dv.w * __logf(rv.w) + (1.f - dv.w) * __logf(1.f - rv.w);
        }
        float tot = block_sum256(s, red);
        if (t == 0) recpart[b] = tot;
    } else if (b < 1024) {
        // pm partials: 8 i's x 64 j's per block; thread = k
        int pb = b - 512;
        int i0 = (pb >> 3) * 8, j0 = (pb & 7) * 64;
        float s[8], a[8];
#pragma unroll
        for (int i = 0; i < 8; i++) {
            s[i] = lat[(i0 + i) * ZDIM + t];
            a[i] = 0.f;
        }
        for (int j = j0; j < j0 + 64; j++) {
            float2 el = evl[j * ZDIM + t];
            float m = mu[j * ZDIM + t];
#pragma unroll
            for (int i = 0; i < 8; i++) {
                float dd = s[i] - m;
                float v = fmaf(dd * dd, el.x, el.y);   // log2-domain density
                a[i] += fast_exp2(v);
            }
        }
#pragma unroll
        for (int i = 0; i < 8; i++)
            part[((pb & 7) * BATCH + i0 + i) * ZDIM + t] = a[i];
    } else {
        // S matrix: 4 i's per block, thread = j within 256-chunk
        int sb = b - 1024;
        int i0 = (sb >> 1) * 4;
        int j = (sb & 1) * 256 + t;
        for (int idx = t; idx < 4 * ZDIM; idx += 256)
            ss[idx] = lat[i0 * ZDIM + idx];
        __syncthreads();
        float a0 = 0.f, a1 = 0.f, a2 = 0.f, a3 = 0.f;
#pragma unroll 4
        for (int k = 0; k < ZDIM; k++) {
            float2 ew = e2wT[k * BATCH + j];
            float s0 = ss[0 * ZDIM + k];
            float s1 = ss[1 * ZDIM + k];
            float s2 = ss[2 * ZDIM + k];
            float s3 = ss[3 * ZDIM + k];
            a0 = fmaf(s0, fmaf(s0, ew.x, ew.y), a0);
            a1 = fmaf(s1, fmaf(s1, ew.x, ew.y), a1);
            a2 = fmaf(s2, fmaf(s2, ew.x, ew.y), a2);
            a3 = fmaf(s3, fmaf(s3, ew.x, ew.y), a3);
        }
        float c = cj[j];
        smat[(i0 + 0) * BATCH + j] = a0 + c;
        smat[(i0 + 1) * BATCH + j] = a1 + c;
        smat[(i0 + 2) * BATCH + j] = a2 + c;
        smat[(i0 + 3) * BATCH + j] = a3 + c;
    }
}

// K3 (512 blocks): block i = merge pm partials -> prod_i, lse over S row i,
// tc_i -> tcpart[i] (agent-scope store); last block sums everything -> out.
__global__ __launch_bounds__(256) void k_finalize(
    const float* __restrict__ part, const float* __restrict__ smat,
    const int* __restrict__ dsz, const float* __restrict__ recpart,
    const float* __restrict__ dwrow, float* __restrict__ tcpart,
    unsigned int* __restrict__ cnt, float* __restrict__ out) {
    __shared__ float red[4];
    int i = blockIdx.x, t = threadIdx.x;
    // merge j-chunk partials -> prod_i = sum_k ln(sum_j exp(v))
    float s = 0.f;
#pragma unroll
    for (int jc = 0; jc < 8; jc++)
        s += part[(jc * BATCH + i) * ZDIM + t];
    float prod_i = block_sum256(__logf(s), red);
    // lse over S row i (max-shifted; S ~ -360)
    float v1 = smat[i * BATCH + t];
    float v2 = smat[i * BATCH + 256 + t];
    float m = wave_reduce_max(fmaxf(v1, v2));
    if ((t & 63) == 0) red[t >> 6] = m;
    __syncthreads();
    m = fmaxf(fmaxf(red[0], red[1]), fmaxf(red[2], red[3]));
    __syncthreads();
    float e = __expf(v1 - m) + __expf(v2 - m);
    float sum = block_sum256(e, red);
    __shared__ bool amLast;
    if (t == 0) {
        float log_norm = __logf(512.f) + __logf((float)dsz[0]);
        float logqz = m + __logf(sum) - log_norm;
        float pm = prod_i - 256.f * log_norm;   // Z * log_norm
        __hip_atomic_store(&tcpart[i], logqz - pm, __ATOMIC_RELAXED,
                           __HIP_MEMORY_SCOPE_AGENT);
        unsigned int old = __hip_atomic_fetch_add(cnt, 1u, __ATOMIC_ACQ_REL,
                                                  __HIP_MEMORY_SCOPE_AGENT);
        amLast = (old == BATCH - 1);
    }
    __syncthreads();
    if (amLast) {
        // recpart/dwrow are cross-kernel (visible at dispatch acquire);
        // tcpart is intra-kernel -> agent-scope loads to bypass stale L2.
        float acc = 0.f;
        float tc1 = __hip_atomic_load(&tcpart[t], __ATOMIC_RELAXED,
                                      __HIP_MEMORY_SCOPE_AGENT);
        float tc2 = __hip_atomic_load(&tcpart[t + 256], __ATOMIC_RELAXED,
                                      __HIP_MEMORY_SCOPE_AGENT);
        acc += tc1 + tc2;
        acc += dwrow[t] + dwrow[t + 256];
        acc -= recpart[t] + recpart[t + 256];
        float tot = block_sum256(acc, red);
        if (t == 0) out[0] = tot * (1.f / 512.f);
    }
}

// ---------------------------------------------------------------- launch

extern "C" void kernel_launch(void* const* d_in, const int* in_sizes, int n_in,
                              void* d_out, int out_size, void* d_ws, size_t ws_size,
                              hipStream_t stream) {
    const float* data   = (const float*)d_in[0];
    const float* recon  = (const float*)d_in[1];
    const float* lat    = (const float*)d_in[2];
    const float* mu     = (const float*)d_in[3];
    const float* logvar = (const float*)d_in[4];
    const int*   dsz    = (const int*)d_in[5];
    float* out = (float*)d_out;

    // workspace layout (float offsets) — every slot fully overwritten each call
    float*  ws      = (float*)d_ws;
    unsigned int* cnt = (unsigned int*)ws;          // [0] (zeroed by K1)
    float*  recpart = ws + 64;                      // 512
    float*  dwrow   = recpart + 512;                // 512
    float*  tcpart  = dwrow + 512;                  // 512
    float*  cj      = tcpart + 512;                 // 512
    float2* evl     = (float2*)(ws + 4096);         // 131072 float2
    float2* e2wT    = (float2*)(ws + 4096 + 262144);// 131072 float2
    float*  part    = ws + 4096 + 524288;           // 8*131072 = 1048576
    float*  smat    = part + 1048576;               // 262144

    k_tables<<<512, 256, 0, stream>>>(mu, logvar, evl, e2wT, cj, dwrow, cnt);
    k_bulk<<<1280, 256, 0, stream>>>((const float4*)data, (const float4*)recon,
                                     lat, evl, mu, part, e2wT, cj, smat, recpart);
    k_finalize<<<512, 256, 0, stream>>>(part, smat, dsz, recpart, dwrow,
                                        tcpart, cnt, out);
}